// Round 5
// baseline (374.218 us; speedup 1.0000x reference)
//
#include <hip/hip_runtime.h>

typedef unsigned short u16;
typedef __bf16 bf16x8 __attribute__((ext_vector_type(8)));
typedef float f32x4 __attribute__((ext_vector_type(4)));
typedef const unsigned int __attribute__((address_space(1))) gu32;
typedef unsigned int __attribute__((address_space(3))) lu32;

#define NN 500
#define LLc 12
#define CC 32
#define MM 384          // CC*LLc rows per batch
#define KP 512          // padded K
#define MT 96           // M tile (8 channels * 12)
#define NT2 128         // N tile
#define XS_S 40         // LDS row stride (bf16) for X tile (hop_fast3)
#define AS_S 40         // LDS row stride (bf16) for A tile (hop_fast3)
#define CT2_S 136       // epilogue C stride
#define TS_S 384        // fallback mix LDS c-stride (floats)
#define AT_ELS 256000   // NN*KP

__device__ __forceinline__ u16 f2bf(float f) {
    union { float f; unsigned u; } cv; cv.f = f;
    unsigned u = cv.u;
    u += 0x7fffu + ((u >> 16) & 1u);    // RNE
    return (u16)(u >> 16);
}
__device__ __forceinline__ float bf2f(u16 s) {
    union { unsigned u; float f; } cv; cv.u = ((unsigned)s) << 16;
    return cv.f;
}

// ---------------- merged A-transpose: z=0,1,2 -> At_s + z*AT_ELS; z>=3 -> At_b + (z-3)*AT_ELS
__global__ __launch_bounds__(256) void atrans_all(
    const float* __restrict__ A0, const float* __restrict__ A1,
    const float* __restrict__ A2, const float* __restrict__ A3,
    u16* __restrict__ At_s, u16* __restrict__ At_b)
{
    __shared__ u16 Ls[32 * 36];
    const int t = threadIdx.x;
    const int n0 = blockIdx.x * 32;
    const int k0 = blockIdx.y * 32;
    const int z = blockIdx.z;
    const float* Ab; u16* Ob;
    if (z == 0)      { Ab = A0; Ob = At_s; }
    else if (z == 1) { Ab = A1; Ob = At_s + (long)AT_ELS; }
    else if (z == 2) { Ab = A2; Ob = At_s + 2L * AT_ELS; }
    else             { Ab = A3 + (long)(z - 3) * NN * NN; Ob = At_b + (long)(z - 3) * AT_ELS; }
    {
        int vl = t >> 3, u = t & 7;
        float4 v = make_float4(0.f, 0.f, 0.f, 0.f);
        if (k0 + vl < NN && n0 + 4 * u + 4 <= NN)
            v = *(const float4*)(Ab + (long)(k0 + vl) * NN + n0 + 4 * u);
        int nb = 4 * u;
        Ls[(nb + 0) * 36 + vl] = f2bf(v.x);
        Ls[(nb + 1) * 36 + vl] = f2bf(v.y);
        Ls[(nb + 2) * 36 + vl] = f2bf(v.z);
        Ls[(nb + 3) * 36 + vl] = f2bf(v.w);
    }
    __syncthreads();
    {
        int row = t >> 3, u = t & 7;
        if (n0 + row < NN)
            *(uint2*)(Ob + (long)(n0 + row) * KP + k0 + 4 * u) = *(const uint2*)(&Ls[row * 36 + 4 * u]);
    }
}

// ---------------- pre-pass: x f32 -> Xt [b][384][512] bf16 (k=v contiguous, zero-padded)
__global__ __launch_bounds__(256) void xpose_kernel(
    const float* __restrict__ x, u16* __restrict__ Xt)
{
    __shared__ u16 Ls[MM * 36];
    const int t = threadIdx.x;
    const int v0 = blockIdx.x * 32;
    const int b  = blockIdx.y;
    #pragma unroll
    for (int j = 0; j < 12; ++j) {
        int f = t + 256 * j;
        int c = f / 96;
        int r = f - c * 96;
        int vl = r / 3;
        int l3 = (r - vl * 3) * 4;
        float4 v = make_float4(0.f, 0.f, 0.f, 0.f);
        if (v0 + vl < NN)
            v = *(const float4*)(x + ((long)b * CC + c) * (NN * LLc) + (long)(v0 + vl) * LLc + l3);
        int mb = (c * LLc + l3) * 36 + vl;
        Ls[mb]       = f2bf(v.x);
        Ls[mb + 36]  = f2bf(v.y);
        Ls[mb + 72]  = f2bf(v.z);
        Ls[mb + 108] = f2bf(v.w);
    }
    __syncthreads();
    #pragma unroll
    for (int j = 0; j < 12; ++j) {
        int f = t + 256 * j;
        int row = f >> 3, u = f & 7;
        *(uint2*)(Xt + ((long)b * MM + row) * KP + v0 + 4 * u) = *(const uint2*)(&Ls[row * 36 + 4 * u]);
    }
}

// ---------------- W prepack for MFMA mix: hi/lo bf16 A-fragments (72 blocks)
// Wp[g][mt][p][lane][8] : o = mt*16 + (lane&15), k = g*32 + (lane>>4)*8 + j
__global__ __launch_bounds__(256) void wpack_kernel(
    const float* __restrict__ W, u16* __restrict__ Wp)
{
    int idx = blockIdx.x * 256 + threadIdx.x;   // < 18432
    int j    = idx & 7;
    int lane = (idx >> 3) & 63;
    int p    = (idx >> 9) & 1;
    int mt   = (idx >> 10) & 1;
    int g    = idx >> 11;           // 0..8
    int o  = mt * 16 + (lane & 15);
    int kk = g * 32 + (lane >> 4) * 8 + j;
    float wv = W[o * 288 + kk];
    u16 hi = f2bf(wv);
    Wp[idx] = (p == 0) ? hi : f2bf(wv - bf2f(hi));
}

// ---------------- hop GEMM v5: 192x128 tile, depth-2 pipelined global_load_lds,
// 3 LDS buffers, counted vmcnt(5), ONE barrier per K-step, setprio around MFMA.
// All operands 512-stride zero-padded; XOR-swizzled LDS (rule #21 both sides).
__global__ __launch_bounds__(256, 2) void hop_fast5(
    const u16* __restrict__ Xsrc, long x_gstride, long x_bstride,
    const u16* __restrict__ At_s,   // g<3: static A, g-stride AT_ELS
    const u16* __restrict__ At_b,   // g==3: batched A, b-stride AT_ELS
    u16* __restrict__ Hout, long h_gstride)
{
    __shared__ __align__(16) u16 smem[30720];   // 3 x 20KB k-step buffers (A 8KB + X 12KB)
    u16* Ct = smem;                             // epilogue reuse [96][136]

    const int t = threadIdx.x;
    const int lane = t & 63;
    const int wv = t >> 6;
    // bijective XCD swizzle over 2048 blocks (2048 % 8 == 0)
    const int f0 = blockIdx.x + 4 * blockIdx.y + 8 * blockIdx.z;   // 0..2047
    const int w  = (f0 & 7) * 256 + (f0 >> 3);
    const int bx = w & 3;
    const int by = (w >> 2) & 1;
    const int zc = w >> 3;
    const int g  = zc & 3;
    const int b  = zc >> 2;
    const int n0 = bx * NT2;
    const int m0 = by * 192;
    const int ln  = lane & 15;
    const int q16 = lane >> 4;

    const u16* Ab = (g < 3) ? (At_s + (long)g * AT_ELS) : (At_b + (long)b * AT_ELS);
    const u16* Xb = Xsrc + (long)g * x_gstride + (long)b * x_bstride;
    u16* Ob = Hout + (long)g * h_gstride + (long)b * ((long)MM * KP);

    const int rbase = lane >> 2;
    const int coff  = (((lane & 3) ^ ((lane >> 3) & 3)) << 3);   // inverse-swizzled src col (u16)
    const int rsel  = ((q16 ^ ((ln >> 1) & 3)) << 3);            // swizzled read col (u16)

    auto STAGE = [&](int kk, int pb) {
        #pragma unroll
        for (int j = 0; j < 5; ++j) {
            int o = (wv * 5 + j) << 10;            // byte offset in 20KB buffer
            const u16* src;
            if (o < 8192) {                         // A region: rows 0..127 (n)
                src = Ab + (long)(n0 + (o >> 6) + rbase) * KP + kk + coff;
            } else {                                // X region: rows 0..191 (m)
                src = Xb + (long)(m0 + (o >> 6) - 128 + rbase) * KP + kk + coff;
            }
            __builtin_amdgcn_global_load_lds((gu32*)src,
                (lu32*)((char*)smem + pb * 20480 + o), 16, 0, 0);
        }
    };

    f32x4 acc[2][12];
    #pragma unroll
    for (int ns = 0; ns < 2; ++ns)
        #pragma unroll
        for (int i = 0; i < 12; ++i)
            #pragma unroll
            for (int r = 0; r < 4; ++r) acc[ns][i][r] = 0.f;

    auto COMPUTE = [&](int pb) {
        const u16* As = smem + pb * 10240;          // u16 units (20KB)
        const u16* Xs = As + 4096;                  // +8KB
        const int rowA0 = wv * 32 + ln;
        bf16x8 b0 = *(const bf16x8*)(&As[rowA0 * 32 + rsel]);
        bf16x8 b1 = *(const bf16x8*)(&As[(rowA0 + 16) * 32 + rsel]);
        __builtin_amdgcn_s_setprio(1);
        #pragma unroll
        for (int i = 0; i < 12; ++i) {
            bf16x8 af = *(const bf16x8*)(&Xs[(i * 16 + ln) * 32 + rsel]);
            acc[0][i] = __builtin_amdgcn_mfma_f32_16x16x32_bf16(af, b0, acc[0][i], 0, 0, 0);
            acc[1][i] = __builtin_amdgcn_mfma_f32_16x16x32_bf16(af, b1, acc[1][i], 0, 0, 0);
        }
        __builtin_amdgcn_s_setprio(0);
    };

    // prologue: 2 K-steps in flight (10 loads/thread)
    STAGE(0, 0);
    STAGE(32, 1);
    int c0 = 0, c1 = 1, c2 = 2;
    #pragma unroll 1
    for (int s = 0; s < 15; ++s) {
        // wait own 5 loads of STAGE(s); leave STAGE(s+1)'s 5 in flight
        asm volatile("s_waitcnt vmcnt(5)" ::: "memory");
        __builtin_amdgcn_s_barrier();               // all waves: buf c0 ready; s-1 reads done
        __builtin_amdgcn_sched_barrier(0);
        if (s <= 13) STAGE(32 * (s + 2), c2);       // overwrites buffer read at iter s-1
        COMPUTE(c0);
        int tmp = c0; c0 = c1; c1 = c2; c2 = tmp;
    }
    asm volatile("s_waitcnt vmcnt(0)" ::: "memory");
    __builtin_amdgcn_s_barrier();
    __builtin_amdgcn_sched_barrier(0);
    COMPUTE(c0);

    // epilogue: two rounds of 96 rows; writes full 512-stride rows (zeros in n>=500 pad)
    #pragma unroll
    for (int h = 0; h < 2; ++h) {
        __syncthreads();
        #pragma unroll
        for (int ns = 0; ns < 2; ++ns) {
            int col = wv * 32 + ns * 16 + ln;
            #pragma unroll
            for (int i6 = 0; i6 < 6; ++i6) {
                int rb = i6 * 16 + (lane >> 4) * 4;
                #pragma unroll
                for (int r = 0; r < 4; ++r)
                    Ct[(rb + r) * CT2_S + col] = f2bf(acc[ns][h * 6 + i6][r]);
            }
        }
        __syncthreads();
        #pragma unroll
        for (int j = 0; j < 12; ++j) {
            int f = t + 256 * j;
            int row = f >> 5, u = f & 31;
            int n = n0 + 4 * u;
            uint2 v = make_uint2(0u, 0u);
            if (n < NN) v = *(const uint2*)(&Ct[row * CT2_S + 4 * u]);
            *(uint2*)(Ob + (long)(m0 + h * 96 + row) * KP + n) = v;
        }
    }
}

// ---------------- merged hop GEMM v3 (mid-tier fallback): 192x128 tile, reg-staged
__global__ __launch_bounds__(256, 3) void hop_fast3(
    const u16* __restrict__ Xsrc, long x_gstride, long x_bstride, int x_rstride, int x_klim,
    const u16* __restrict__ At_s,
    const u16* __restrict__ At_b,
    u16* __restrict__ Hout, long h_gstride)
{
    __shared__ __align__(16) u16 smem[13056];
    u16* As = smem;          // [128][40]
    u16* Xs = smem + 5120;   // [192][40]
    u16* Ct = smem;          // [96][136]

    const int t = threadIdx.x;
    const int lane = t & 63;
    const int wv = t >> 6;
    const int f0 = blockIdx.x + 4 * blockIdx.y + 8 * blockIdx.z;
    const int w  = (f0 & 7) * 256 + (f0 >> 3);
    const int bx = w & 3;
    const int by = (w >> 2) & 1;
    const int zc = w >> 3;
    const int g  = zc & 3;
    const int b  = zc >> 2;
    const int n0 = bx * NT2;
    const int m0 = by * 192;
    const int ln = lane & 15;
    const int q8 = (lane >> 4) * 8;

    const u16* Ab = (g < 3) ? (At_s + (long)g * AT_ELS) : (At_b + (long)b * AT_ELS);
    const u16* Xb = Xsrc + (long)g * x_gstride + (long)b * x_bstride;
    u16* Ob = Hout + (long)g * h_gstride + (long)b * ((long)MM * NN);

    uint2 pa[4], px[6];
    auto loadA = [&](int k0) {
        #pragma unroll
        for (int j = 0; j < 4; ++j) {
            int f = t + 256 * j;
            int n = f >> 3, u = f & 7;
            uint2 v = make_uint2(0u, 0u);
            if (n0 + n < NN)
                v = *(const uint2*)(Ab + (long)(n0 + n) * KP + k0 + 4 * u);
            pa[j] = v;
        }
    };
    auto loadX = [&](int k0) {
        #pragma unroll
        for (int j = 0; j < 6; ++j) {
            int f = t + 256 * j;
            int r = f >> 3, u = f & 7;
            int k = k0 + 4 * u;
            uint2 v = make_uint2(0u, 0u);
            if (k < x_klim)
                v = *(const uint2*)(Xb + (long)(m0 + r) * x_rstride + k);
            px[j] = v;
        }
    };

    f32x4 acc[2][12];
    #pragma unroll
    for (int ns = 0; ns < 2; ++ns)
        #pragma unroll
        for (int i = 0; i < 12; ++i)
            #pragma unroll
            for (int r = 0; r < 4; ++r) acc[ns][i][r] = 0.f;

    loadA(0);
    loadX(0);
    #pragma unroll 1
    for (int s = 0; s < 16; ++s) {
        __syncthreads();
        #pragma unroll
        for (int j = 0; j < 4; ++j) {
            int f = t + 256 * j;
            *(uint2*)(&As[(f >> 3) * AS_S + 4 * (f & 7)]) = pa[j];
        }
        #pragma unroll
        for (int j = 0; j < 6; ++j) {
            int f = t + 256 * j;
            *(uint2*)(&Xs[(f >> 3) * XS_S + 4 * (f & 7)]) = px[j];
        }
        if (s < 15) {
            loadA(32 * (s + 1));
            loadX(32 * (s + 1));
        }
        __syncthreads();
        bf16x8 b0 = *(const bf16x8*)(&As[(wv * 32 + ln) * AS_S + q8]);
        bf16x8 b1 = *(const bf16x8*)(&As[(wv * 32 + 16 + ln) * AS_S + q8]);
        #pragma unroll
        for (int i = 0; i < 12; ++i) {
            bf16x8 af = *(const bf16x8*)(&Xs[(i * 16 + ln) * XS_S + q8]);
            acc[0][i] = __builtin_amdgcn_mfma_f32_16x16x32_bf16(af, b0, acc[0][i], 0, 0, 0);
            acc[1][i] = __builtin_amdgcn_mfma_f32_16x16x32_bf16(af, b1, acc[1][i], 0, 0, 0);
        }
    }

    #pragma unroll
    for (int h = 0; h < 2; ++h) {
        __syncthreads();
        #pragma unroll
        for (int ns = 0; ns < 2; ++ns) {
            int col = wv * 32 + ns * 16 + ln;
            #pragma unroll
            for (int i6 = 0; i6 < 6; ++i6) {
                int rb = i6 * 16 + (lane >> 4) * 4;
                #pragma unroll
                for (int r = 0; r < 4; ++r)
                    Ct[(rb + r) * CT2_S + col] = f2bf(acc[ns][h * 6 + i6][r]);
            }
        }
        __syncthreads();
        #pragma unroll
        for (int j = 0; j < 12; ++j) {
            int f = t + 256 * j;
            int row = f >> 5, u = f & 31;
            int n = n0 + 4 * u;
            if (n < NN)
                *(uint2*)(Ob + (long)(m0 + h * 96 + row) * NN + n) = *(const uint2*)(&Ct[row * CT2_S + 4 * u]);
        }
    }
}

// ---------------- MFMA mix: out[o][(l,n)] = sum_c (Whi+Wlo)[o][c] * Hcat[c][(l,n)] + bias
// grid (8 n-tiles of 64, 64 b), 512 threads. 9 K-groups of 32 channels.
__global__ __launch_bounds__(512, 4) void mix_mfma(
    const u16* __restrict__ Xt,
    const u16* __restrict__ H,
    const u16* __restrict__ Wp,
    const float* __restrict__ bias,
    float* __restrict__ out,
    long h_gs, long h_bs, int h_rs)
{
    __shared__ __align__(16) char smem[50176];   // tile: 384*64*2 = 49152 B ; Ct reuse
    u16*   Ls = (u16*)smem;
    float* Ct = (float*)smem;

    const int t   = threadIdx.x;
    const int wg  = blockIdx.y * 8 + blockIdx.x;
    const int swz = (wg & 7) * 64 + (wg >> 3);   // chunked XCD swizzle
    const int bx  = swz & 7;
    const int b   = swz >> 3;
    const int n0  = bx * 64;
    const int w    = t >> 6;          // wave 0..7
    const int lane = t & 63;
    const int kq   = lane >> 4;
    const int ln   = lane & 15;
    const int srow   = lane >> 3;
    const int schunk = (lane & 7) * 8;

    f32x4 acc[6][2];
    #pragma unroll
    for (int i = 0; i < 6; ++i)
        #pragma unroll
        for (int m = 0; m < 2; ++m)
            #pragma unroll
            for (int r = 0; r < 4; ++r) acc[i][m][r] = 0.f;

    #pragma unroll 1
    for (int g = 0; g < 9; ++g) {
        const u16* base; int rs;
        if (g == 0) { base = Xt + (long)b * (MM * KP); rs = KP; }
        else {
            int gg = g - 1;
            int buf = (gg & 1) ? 4 + (gg >> 1) : (gg >> 1);
            base = H + (long)buf * h_gs + (long)b * h_bs; rs = h_rs;
        }
        __syncthreads();
        #pragma unroll
        for (int i = 0; i < 6; ++i) {
            int r0 = (w * 6 + i) * 8;
            const u16* src = base + (long)(r0 + srow) * rs + n0 + schunk;
            __builtin_amdgcn_global_load_lds((gu32*)src, (lu32*)(Ls + r0 * 64), 16, 0, 0);
        }
        asm volatile("s_waitcnt vmcnt(0)" ::: "memory");
        __syncthreads();
        uint4 wf[2][2];
        #pragma unroll
        for (int mt = 0; mt < 2; ++mt)
            #pragma unroll
            for (int p = 0; p < 2; ++p)
                wf[mt][p] = *(const uint4*)(Wp + ((((g * 2 + mt) * 2 + p) * 64 + lane) * 8));
        #pragma unroll
        for (int i = 0; i < 6; ++i) {
            int ct = w * 6 + i;
            int off0 = kq * 6144 + (ct >> 2) * 64 + (ct & 3) * 16 + ln;
            union { u16 s[8]; bf16x8 v; } fb;
            #pragma unroll
            for (int j = 0; j < 8; ++j) fb.s[j] = Ls[off0 + j * 768];
            #pragma unroll
            for (int mt = 0; mt < 2; ++mt) {
                acc[i][mt] = __builtin_amdgcn_mfma_f32_16x16x32_bf16(*(const bf16x8*)&wf[mt][0], fb.v, acc[i][mt], 0, 0, 0);
                acc[i][mt] = __builtin_amdgcn_mfma_f32_16x16x32_bf16(*(const bf16x8*)&wf[mt][1], fb.v, acc[i][mt], 0, 0, 0);
            }
        }
    }

    #pragma unroll
    for (int mt = 0; mt < 2; ++mt) {
        __syncthreads();
        #pragma unroll
        for (int i = 0; i < 6; ++i) {
            int col = (w * 6 + i) * 16 + ln;
            #pragma unroll
            for (int r = 0; r < 4; ++r)
                Ct[(kq * 4 + r) * 781 + col] = acc[i][mt][r];
        }
        __syncthreads();
        int o16 = t >> 5, u = t & 31;
        int og = mt * 16 + o16;
        float bs = bias[og];
        float* ob = out + (((long)b * CC + og) * NN + n0) * 12L;
        #pragma unroll
        for (int j2 = 0; j2 < 2; ++j2) {
            int n = u + 32 * j2;
            if (n0 + n < NN) {
                float v[12];
                #pragma unroll
                for (int l = 0; l < 12; ++l) v[l] = Ct[o16 * 781 + l * 64 + n] + bs;
                #pragma unroll
                for (int q = 0; q < 3; ++q)
                    *(float4*)(ob + (long)n * 12 + q * 4) = *(const float4*)&v[q * 4];
            }
        }
    }
}

// ---------------- single-pass mix (mid-tier ws, VALU)
__global__ __launch_bounds__(256, 3) void mix_all(
    const u16* __restrict__ Xt,
    const u16* __restrict__ H,
    const float* __restrict__ W,
    const float* __restrict__ bias,
    float* __restrict__ out)
{
    __shared__ __align__(16) float smem[96 * 36 + 288 * 33];
    float* ts = smem;
    float* Ws = smem + 96 * 36;

    const int t  = threadIdx.x;
    const int b  = blockIdx.y;
    const int w0 = blockIdx.x * 32;
    const int o  = t & 31;
    const int wq = t >> 5;
    const int w4 = wq * 4;
    const long HBUF = (long)64 * MM * NN;

    #pragma unroll
    for (int j = 0; j < 36; ++j) {
        int f = t + 256 * j;
        int oo = f & 31, ci = f >> 5;
        Ws[ci * 33 + oo] = W[oo * 288 + ci];
    }

    float acc[4][12];
    #pragma unroll
    for (int k = 0; k < 4; ++k)
        #pragma unroll
        for (int l = 0; l < 12; ++l) acc[k][l] = 0.f;

    uint2 px[3];
    auto loadq = [&](int q) {
        int g = q >> 2, c0 = (q & 3) << 3;
        const u16* base; int rs;
        if (g == 0) { base = Xt + (long)b * (MM * KP); rs = KP; }
        else {
            int gg = g - 1, i = gg >> 1;
            int buf = (gg & 1) ? 4 + i : i;
            base = H + (long)buf * HBUF + (long)b * ((long)MM * NN); rs = NN;
        }
        int m0c = c0 * 12;
        #pragma unroll
        for (int j = 0; j < 3; ++j) {
            int f = t + 256 * j;
            int r = f >> 3, u = f & 7;
            px[j] = *(const uint2*)(base + (long)(m0c + r) * rs + w0 + 4 * u);
        }
    };

    loadq(0);
    #pragma unroll 1
    for (int q = 0; q < 36; ++q) {
        __syncthreads();
        #pragma unroll
        for (int j = 0; j < 3; ++j) {
            int f = t + 256 * j;
            int r = f >> 3, u = f & 7;
            uint2 raw = px[j];
            float4 v = make_float4(bf2f((u16)(raw.x & 0xffffu)), bf2f((u16)(raw.x >> 16)),
                                   bf2f((u16)(raw.y & 0xffffu)), bf2f((u16)(raw.y >> 16)));
            *(float4*)(&ts[r * 36 + 4 * u]) = v;
        }
        if (q < 35) loadq(q + 1);
        __syncthreads();
        int g = q >> 2, c0 = (q & 3) << 3;
        #pragma unroll 1
        for (int cl = 0; cl < 8; ++cl) {
            float wgt = Ws[(g * 32 + c0 + cl) * 33 + o];
            #pragma unroll
            for (int l = 0; l < 12; ++l) {
                float4 h = *(const float4*)(&ts[(cl * 12 + l) * 36 + w4]);
                acc[0][l] += wgt * h.x;
                acc[1][l] += wgt * h.y;
                acc[2][l] += wgt * h.z;
                acc[3][l] += wgt * h.w;
            }
        }
    }

    #pragma unroll 1
    for (int r = 0; r < 4; ++r) {
        __syncthreads();
        if ((o >> 3) == r) {
            int ol = o & 7;
            #pragma unroll
            for (int k = 0; k < 4; ++k)
                #pragma unroll
                for (int l = 0; l < 12; ++l)
                    ts[ol * 388 + (w4 + k) * 12 + l] = acc[k][l];
        }
        __syncthreads();
        #pragma unroll
        for (int j = 0; j < 3; ++j) {
            int f4 = t + 256 * j;
            int ol = f4 / 96;
            int rem = f4 - ol * 96;
            int w  = rem / 3;
            int lq = rem - w * 3;
            if (w0 + w < NN) {
                float4 v = *(const float4*)(&ts[ol * 388 + w * 12 + lq * 4]);
                float bs = bias[r * 8 + ol];
                v.x += bs; v.y += bs; v.z += bs; v.w += bs;
                *(float4*)(out + (((long)b * CC + r * 8 + ol) * NN + w0 + w) * LLc + lq * 4) = v;
            }
        }
    }
}

// ======================================================================
// Fallback path (R3-equivalent) — used when ws < 256 MB tier
// ======================================================================
__global__ __launch_bounds__(256, 4) void hop_fast(
    const u16* __restrict__ Xsrc, long x_bstride, int x_rstride, int x_klim,
    const u16* __restrict__ At,   long a_bstride,
    u16* __restrict__ hout)
{
    __shared__ __align__(16) u16 smem[13056];
    u16* As = smem;
    u16* Xs = smem + 5120;
    u16* Ct = smem;

    const int t = threadIdx.x;
    const int lane = t & 63;
    const int wv = t >> 6;
    const int n0 = blockIdx.x * NT2;
    const int m0 = blockIdx.y * MT;
    const int b  = blockIdx.z;
    const int ln = lane & 15;
    const int q8 = (lane >> 4) * 8;

    const u16* Ab = At + (long)b * a_bstride;
    const u16* Xb = Xsrc + (long)b * x_bstride;

    uint2 pa[4], px[3];
    auto loadA = [&](int k0) {
        #pragma unroll
        for (int j = 0; j < 4; ++j) {
            int f = t + 256 * j;
            int n = f >> 3, u = f & 7;
            uint2 v = make_uint2(0u, 0u);
            if (n0 + n < NN)
                v = *(const uint2*)(Ab + (long)(n0 + n) * KP + k0 + 4 * u);
            pa[j] = v;
        }
    };
    auto loadX = [&](int k0) {
        #pragma unroll
        for (int j = 0; j < 3; ++j) {
            int f = t + 256 * j;
            int r = f >> 3, u = f & 7;
            int k = k0 + 4 * u;
            uint2 v = make_uint2(0u, 0u);
            if (k < x_klim)
                v = *(const uint2*)(Xb + (long)(m0 + r) * x_rstride + k);
            px[j] = v;
        }
    };

    f32x4 acc[2][6];
    #pragma unroll
    for (int ns = 0; ns < 2; ++ns)
        #pragma unroll
        for (int i = 0; i < 6; ++i)
            #pragma unroll
            for (int r = 0; r < 4; ++r) acc[ns][i][r] = 0.f;

    loadA(0);
    loadX(0);
    #pragma unroll 1
    for (int s = 0; s < 16; ++s) {
        __syncthreads();
        #pragma unroll
        for (int j = 0; j < 4; ++j) {
            int f = t + 256 * j;
            *(uint2*)(&As[(f >> 3) * AS_S + 4 * (f & 7)]) = pa[j];
        }
        #pragma unroll
        for (int j = 0; j < 3; ++j) {
            int f = t + 256 * j;
            *(uint2*)(&Xs[(f >> 3) * XS_S + 4 * (f & 7)]) = px[j];
        }
        if (s < 15) {
            loadA(32 * (s + 1));
            loadX(32 * (s + 1));
        }
        __syncthreads();
        bf16x8 af[6];
        #pragma unroll
        for (int i = 0; i < 6; ++i)
            af[i] = *(const bf16x8*)(&Xs[(i * 16 + ln) * XS_S + q8]);
        #pragma unroll
        for (int ns = 0; ns < 2; ++ns) {
            bf16x8 bfr = *(const bf16x8*)(&As[(wv * 32 + ns * 16 + ln) * AS_S + q8]);
            #pragma unroll
            for (int i = 0; i < 6; ++i)
                acc[ns][i] = __builtin_amdgcn_mfma_f32_16x16x32_bf16(af[i], bfr, acc[ns][i], 0, 0, 0);
        }
    }

    __syncthreads();
    #pragma unroll
    for (int ns = 0; ns < 2; ++ns) {
        int col = wv * 32 + ns * 16 + ln;
        #pragma unroll
        for (int i = 0; i < 6; ++i) {
            int rb = i * 16 + (lane >> 4) * 4;
            #pragma unroll
            for (int r = 0; r < 4; ++r)
                Ct[(rb + r) * CT2_S + col] = f2bf(acc[ns][i][r]);
        }
    }
    __syncthreads();
    u16* Ob = hout + (long)b * ((long)MM * NN);
    #pragma unroll
    for (int j = 0; j < 12; ++j) {
        int f = t + 256 * j;
        int row = f >> 5, u = f & 31;
        int n = n0 + 4 * u;
        if (n < NN)
            *(uint2*)(Ob + (long)(m0 + row) * NN + n) = *(const uint2*)(&Ct[row * CT2_S + 4 * u]);
    }
}

__global__ __launch_bounds__(256, 2) void mix_kernel(
    const float* __restrict__ x,
    const u16* __restrict__ h1,
    const u16* __restrict__ h2,
    const float* __restrict__ W,
    const float* __restrict__ bias,
    int blk1, int blk2,
    float* __restrict__ out, int init)
{
    __shared__ __align__(16) float smem[CC * TS_S + 3 * 1056];
    float* ts = smem;
    float* Ws = smem + CC * TS_S;

    const int t = threadIdx.x;
    const int b = blockIdx.y;
    const int w0 = blockIdx.x * 32;
    const int o  = t & 15;
    const int wg = (t >> 4) & 7;
    const int lh = t >> 7;

    #pragma unroll
    for (int j = 0; j < 4; ++j) {
        int f = t + 256 * j;
        int oo = f & 31, c = f >> 5;
        Ws[c * 33 + oo]        = W[oo * 288 + blk1 * 32 + c];
        Ws[1056 + c * 33 + oo] = W[oo * 288 + blk2 * 32 + c];
        if (init) Ws[2112 + c * 33 + oo] = W[oo * 288 + c];
    }

    float acc2[2][4][6];
    #pragma unroll
    for (int a = 0; a < 2; ++a)
        #pragma unroll
        for (int q = 0; q < 4; ++q)
            #pragma unroll
            for (int l = 0; l < 6; ++l) acc2[a][q][l] = 0.f;

    auto stage_h = [&](const u16* h) {
        #pragma unroll
        for (int j = 0; j < 12; ++j) {
            int f = t + 256 * j;
            int row = f >> 3, u = f & 7;
            int w = w0 + 4 * u;
            uint2 raw = make_uint2(0u, 0u);
            if (w < NN)
                raw = *(const uint2*)(h + ((long)b * MM + row) * NN + w);
            int c = row / 12;
            int l = row - c * 12;
            float* dst = &ts[c * TS_S + l * 32 + 4 * u];
            dst[0] = bf2f((u16)(raw.x & 0xffffu));
            dst[1] = bf2f((u16)(raw.x >> 16));
            dst[2] = bf2f((u16)(raw.y & 0xffffu));
            dst[3] = bf2f((u16)(raw.y >> 16));
        }
    };
    auto accum = [&](const float* Wg) {
        for (int c = 0; c < CC; ++c) {
            float w1 = Wg[c * 33 + o];
            float w2 = Wg[c * 33 + o + 16];
            #pragma unroll
            for (int l6 = 0; l6 < 6; ++l6) {
                const float4 hv = *(const float4*)(&ts[c * TS_S + (lh * 6 + l6) * 32 + wg * 4]);
                acc2[0][0][l6] += w1 * hv.x;
                acc2[0][1][l6] += w1 * hv.y;
                acc2[0][2][l6] += w1 * hv.z;
                acc2[0][3][l6] += w1 * hv.w;
                acc2[1][0][l6] += w2 * hv.x;
                acc2[1][1][l6] += w2 * hv.y;
                acc2[1][2][l6] += w2 * hv.z;
                acc2[1][3][l6] += w2 * hv.w;
            }
        }
    };

    if (init) {
        #pragma unroll
        for (int j = 0; j < 12; ++j) {
            int f = t + 256 * j;
            int c = f / 96;
            int r = f - c * 96;
            int w = r / 3;
            int q = r - w * 3;
            float4 v = make_float4(0.f, 0.f, 0.f, 0.f);
            if (w0 + w < NN)
                v = *(const float4*)(x + ((long)b * CC + c) * (NN * LLc) + (long)(w0 + w) * LLc + q * 4);
            float* dst = &ts[c * TS_S + (q * 4) * 32 + w];
            dst[0]  = v.x; dst[32] = v.y; dst[64] = v.z; dst[96] = v.w;
        }
        __syncthreads();
        accum(Ws + 2112);
        __syncthreads();
    }
    stage_h(h1);
    __syncthreads();
    accum(Ws);
    __syncthreads();
    stage_h(h2);
    __syncthreads();
    accum(Ws + 1056);

    #pragma unroll
    for (int oh = 0; oh < 2; ++oh) {
        int oo = o + 16 * oh;
        float bs = init ? bias[oo] : 0.f;
        #pragma unroll
        for (int q = 0; q < 4; ++q) {
            int w = w0 + wg * 4 + q;
            if (w < NN) {
                float* op = out + ((long)b * CC + oo) * (NN * LLc) + (long)w * LLc + lh * 6;
                #pragma unroll
                for (int p = 0; p < 3; ++p) {
                    float2* pp = (float2*)op + p;
                    float2 v;
                    if (init) {
                        v.x = bs + acc2[oh][q][2 * p];
                        v.y = bs + acc2[oh][q][2 * p + 1];
                    } else {
                        v = *pp;
                        v.x += acc2[oh][q][2 * p];
                        v.y += acc2[oh][q][2 * p + 1];
                    }
                    *pp = v;
                }
            }
        }
    }
}

extern "C" void kernel_launch(void* const* d_in, const int* in_sizes, int n_in,
                              void* d_out, int out_size, void* d_ws, size_t ws_size,
                              hipStream_t stream) {
    const float* x    = (const float*)d_in[0];
    const float* A0   = (const float*)d_in[1];
    const float* A1   = (const float*)d_in[2];
    const float* A2   = (const float*)d_in[3];
    const float* A3   = (const float*)d_in[4];
    const float* W    = (const float*)d_in[5];
    const float* bias = (const float*)d_in[6];
    float* out = (float*)d_out;
    char* ws = (char*)d_ws;

    const size_t HBUF_ELS  = (size_t)64 * MM * NN;          // 12,288,000
    const size_t H8_BYTES  = 8 * HBUF_ELS * 2;              // 196,608,000
    const size_t AT_BYTES  = (size_t)AT_ELS * 2;            // 512,000
    const size_t A3T_BYTES = 64 * AT_BYTES;                 // 32,768,000
    const size_t XT_BYTES  = (size_t)64 * MM * KP * 2;      // 25,165,824
    const size_t need2 = H8_BYTES + 3 * AT_BYTES + A3T_BYTES + XT_BYTES;  // 256,077,824
    const size_t WPK_BYTES = 36864;
    const size_t need3 = need2 + WPK_BYTES;
    // padded-H tier: all M x N buffers [384][512]
    const size_t HB2_ELS  = (size_t)64 * MM * KP;           // 12,582,912 per buffer
    const size_t H8B_PAD  = 8 * HB2_ELS * 2;                // 201,326,592
    const size_t need4 = H8B_PAD + 3 * AT_BYTES + A3T_BYTES + XT_BYTES + WPK_BYTES; // 260,833,280

    dim3 blk(256);
    dim3 hgrid(4, 2, 256);

    if (ws_size >= need4) {
        // ---------- fastest path: pipelined gload_lds hops + MFMA mix ----------
        u16* Hb   = (u16*)ws;
        u16* At_s = (u16*)(ws + H8B_PAD);
        u16* A3t  = At_s + 3L * AT_ELS;
        u16* Xt   = (u16*)(ws + H8B_PAD + 3 * AT_BYTES + A3T_BYTES);
        u16* Wpk  = Xt + (size_t)64 * MM * KP;

        atrans_all<<<dim3(16, 16, 67), blk, 0, stream>>>(A0, A1, A2, A3, At_s, A3t);
        xpose_kernel<<<dim3(16, 64), blk, 0, stream>>>(x, Xt);
        wpack_kernel<<<dim3(72), blk, 0, stream>>>(W, Wpk);
        hop_fast5<<<hgrid, blk, 0, stream>>>(
            Xt, 0L, (long)MM * KP, At_s, A3t, Hb, (long)HB2_ELS);
        hop_fast5<<<hgrid, blk, 0, stream>>>(
            Hb, (long)HB2_ELS, (long)MM * KP, At_s, A3t,
            Hb + 4 * HB2_ELS, (long)HB2_ELS);
        mix_mfma<<<dim3(8, 64), dim3(512), 0, stream>>>(
            Xt, Hb, Wpk, bias, out, (long)HB2_ELS, (long)MM * KP, KP);
        return;
    }

    if (ws_size >= need3) {
        // ---------- round-3 proven path: reg-staged hops (500-stride H) + MFMA mix ----------
        u16* Hb   = (u16*)ws;
        u16* At_s = (u16*)(ws + H8_BYTES);
        u16* A3t  = At_s + 3L * AT_ELS;
        u16* Xt   = (u16*)(ws + H8_BYTES + 3 * AT_BYTES + A3T_BYTES);
        u16* Wpk  = (u16*)(ws + need2);

        atrans_all<<<dim3(16, 16, 67), blk, 0, stream>>>(A0, A1, A2, A3, At_s, A3t);
        xpose_kernel<<<dim3(16, 64), blk, 0, stream>>>(x, Xt);
        wpack_kernel<<<dim3(72), blk, 0, stream>>>(W, Wpk);
        hop_fast3<<<hgrid, blk, 0, stream>>>(
            Xt, 0L, (long)MM * KP, KP, KP, At_s, A3t, Hb, (long)HBUF_ELS);
        hop_fast3<<<hgrid, blk, 0, stream>>>(
            Hb, (long)HBUF_ELS, (long)MM * NN, NN, NN, At_s, A3t,
            Hb + 4 * HBUF_ELS, (long)HBUF_ELS);
        mix_mfma<<<dim3(8, 64), dim3(512), 0, stream>>>(
            Xt, Hb, Wpk, bias, out, (long)HBUF_ELS, (long)MM * NN, NN);
        return;
    }

    if (ws_size >= need2) {
        // ---------- mid tier: VALU mix ----------
        u16* H    = (u16*)ws;
        u16* At_s = (u16*)(ws + H8_BYTES);
        u16* A3t  = At_s + 3L * AT_ELS;
        u16* Xt   = (u16*)(ws + H8_BYTES + 3 * AT_BYTES + A3T_BYTES);

        atrans_all<<<dim3(16, 16, 67), blk, 0, stream>>>(A0, A1, A2, A3, At_s, A3t);
        xpose_kernel<<<dim3(16, 64), blk, 0, stream>>>(x, Xt);
        hop_fast3<<<hgrid, blk, 0, stream>>>(
            Xt, 0L, (long)MM * KP, KP, KP, At_s, A3t, H, (long)HBUF_ELS);
        hop_fast3<<<hgrid, blk, 0, stream>>>(
            H, (long)HBUF_ELS, (long)MM * NN, NN, NN, At_s, A3t,
            H + 4 * HBUF_ELS, (long)HBUF_ELS);
        mix_all<<<dim3(16, 64), blk, 0, stream>>>(Xt, H, W, bias, out);
        return;
    }

    // ---------- fallback (R3 path) ----------
    const size_t H_BYTES   = HBUF_ELS * 2;
    const size_t need_at   = 2 * H_BYTES + 3 * AT_BYTES + A3T_BYTES;

    u16* H1 = (u16*)ws;
    u16* H2 = (u16*)(ws + H_BYTES);
    u16* At0 = (u16*)(ws + 2 * H_BYTES);
    u16* A3t = At0 + 3L * AT_ELS;
    u16* Xt  = (u16*)(ws + need_at);

    dim3 fgrid(4, 4, 64);
    dim3 mgrid(16, 64);

    xpose_kernel<<<dim3(16, 64), blk, 0, stream>>>(x, Xt);
    atrans_all<<<dim3(16, 16, 67), blk, 0, stream>>>(A0, A1, A2, A3, At0, A3t);

    const long XT_BS = (long)MM * KP;
    const long H_BS  = (long)MM * NN;
    u16* Atp[4] = {At0, At0 + (long)AT_ELS, At0 + 2L * AT_ELS, A3t};

    for (int i = 0; i < 4; ++i) {
        long a_bs = (i == 3) ? (long)AT_ELS : 0;
        hop_fast<<<fgrid, blk, 0, stream>>>(Xt, XT_BS, KP, KP, Atp[i], a_bs, H1);
        hop_fast<<<fgrid, blk, 0, stream>>>(H1, H_BS, NN, NN, Atp[i], a_bs, H2);
        mix_kernel<<<mgrid, blk, 0, stream>>>(i == 0 ? x : nullptr, H1, H2, W, bias,
                                              2 * i + 1, 2 * i + 2, out, i == 0 ? 1 : 0);
    }
}

// Round 6
// 362.132 us; speedup vs baseline: 1.0334x; 1.0334x over previous
//
#include <hip/hip_runtime.h>

typedef unsigned short u16;
typedef __bf16 bf16x8 __attribute__((ext_vector_type(8)));
typedef float f32x4 __attribute__((ext_vector_type(4)));
typedef const unsigned int __attribute__((address_space(1))) gu32;
typedef unsigned int __attribute__((address_space(3))) lu32;

#define NN 500
#define LLc 12
#define CC 32
#define MM 384          // CC*LLc rows per batch
#define KP 512          // padded K
#define MT 96           // M tile (fallback)
#define NT2 128         // N tile
#define XS_S 40         // LDS row stride (bf16) for X tile (hop_fast3)
#define AS_S 40         // LDS row stride (bf16) for A tile (hop_fast3)
#define CT2_S 136       // epilogue C stride
#define TS_S 384        // fallback mix LDS c-stride (floats)
#define AT_ELS 256000   // NN*KP

__device__ __forceinline__ u16 f2bf(float f) {
    union { float f; unsigned u; } cv; cv.f = f;
    unsigned u = cv.u;
    u += 0x7fffu + ((u >> 16) & 1u);    // RNE
    return (u16)(u >> 16);
}
__device__ __forceinline__ float bf2f(u16 s) {
    union { unsigned u; float f; } cv; cv.u = ((unsigned)s) << 16;
    return cv.f;
}

// ---------------- merged pre-pass: atrans (id<17152) | xpose (id<18176) | wpack (rest)
__global__ __launch_bounds__(256) void prep_all(
    const float* __restrict__ x,
    const float* __restrict__ A0, const float* __restrict__ A1,
    const float* __restrict__ A2, const float* __restrict__ A3,
    u16* __restrict__ At_s, u16* __restrict__ At_b,
    u16* __restrict__ Xt,
    const float* __restrict__ W, u16* __restrict__ Wp)
{
    __shared__ u16 Ls[MM * 36];
    const int id = blockIdx.x;
    const int t = threadIdx.x;

    if (id < 17152) {
        // ---- A-transpose: z = id>>8; n0/k0 from id&255
        int rem = id & 255;
        int z  = id >> 8;
        int n0 = (rem & 15) * 32;
        int k0 = (rem >> 4) * 32;
        const float* Ab; u16* Ob;
        if (z == 0)      { Ab = A0; Ob = At_s; }
        else if (z == 1) { Ab = A1; Ob = At_s + (long)AT_ELS; }
        else if (z == 2) { Ab = A2; Ob = At_s + 2L * AT_ELS; }
        else             { Ab = A3 + (long)(z - 3) * NN * NN; Ob = At_b + (long)(z - 3) * AT_ELS; }
        {
            int vl = t >> 3, u = t & 7;
            float4 v = make_float4(0.f, 0.f, 0.f, 0.f);
            if (k0 + vl < NN && n0 + 4 * u + 4 <= NN)
                v = *(const float4*)(Ab + (long)(k0 + vl) * NN + n0 + 4 * u);
            int nb = 4 * u;
            Ls[(nb + 0) * 36 + vl] = f2bf(v.x);
            Ls[(nb + 1) * 36 + vl] = f2bf(v.y);
            Ls[(nb + 2) * 36 + vl] = f2bf(v.z);
            Ls[(nb + 3) * 36 + vl] = f2bf(v.w);
        }
        __syncthreads();
        {
            int row = t >> 3, u = t & 7;
            if (n0 + row < NN)
                *(uint2*)(Ob + (long)(n0 + row) * KP + k0 + 4 * u) = *(const uint2*)(&Ls[row * 36 + 4 * u]);
        }
    } else if (id < 18176) {
        // ---- x f32 -> Xt [b][384][512] bf16
        int jj = id - 17152;
        int v0 = (jj & 15) * 32;
        int b  = jj >> 4;
        #pragma unroll
        for (int j = 0; j < 12; ++j) {
            int f = t + 256 * j;
            int c = f / 96;
            int r = f - c * 96;
            int vl = r / 3;
            int l3 = (r - vl * 3) * 4;
            float4 v = make_float4(0.f, 0.f, 0.f, 0.f);
            if (v0 + vl < NN)
                v = *(const float4*)(x + ((long)b * CC + c) * (NN * LLc) + (long)(v0 + vl) * LLc + l3);
            int mb = (c * LLc + l3) * 36 + vl;
            Ls[mb]       = f2bf(v.x);
            Ls[mb + 36]  = f2bf(v.y);
            Ls[mb + 72]  = f2bf(v.z);
            Ls[mb + 108] = f2bf(v.w);
        }
        __syncthreads();
        #pragma unroll
        for (int j = 0; j < 12; ++j) {
            int f = t + 256 * j;
            int row = f >> 3, u = f & 7;
            *(uint2*)(Xt + ((long)b * MM + row) * KP + v0 + 4 * u) = *(const uint2*)(&Ls[row * 36 + 4 * u]);
        }
    } else {
        // ---- W prepack: hi/lo bf16 A-fragments
        int idx = (id - 18176) * 256 + t;   // < 18432
        int j    = idx & 7;
        int lane = (idx >> 3) & 63;
        int p    = (idx >> 9) & 1;
        int mt   = (idx >> 10) & 1;
        int g    = idx >> 11;
        int o  = mt * 16 + (lane & 15);
        int kk = g * 32 + (lane >> 4) * 8 + j;
        float wv = W[o * 288 + kk];
        u16 hi = f2bf(wv);
        Wp[idx] = (p == 0) ? hi : f2bf(wv - bf2f(hi));
    }
}

// ---- standalone copies for fallback tiers
__global__ __launch_bounds__(256) void atrans_all(
    const float* __restrict__ A0, const float* __restrict__ A1,
    const float* __restrict__ A2, const float* __restrict__ A3,
    u16* __restrict__ At_s, u16* __restrict__ At_b)
{
    __shared__ u16 Ls[32 * 36];
    const int t = threadIdx.x;
    const int n0 = blockIdx.x * 32;
    const int k0 = blockIdx.y * 32;
    const int z = blockIdx.z;
    const float* Ab; u16* Ob;
    if (z == 0)      { Ab = A0; Ob = At_s; }
    else if (z == 1) { Ab = A1; Ob = At_s + (long)AT_ELS; }
    else if (z == 2) { Ab = A2; Ob = At_s + 2L * AT_ELS; }
    else             { Ab = A3 + (long)(z - 3) * NN * NN; Ob = At_b + (long)(z - 3) * AT_ELS; }
    {
        int vl = t >> 3, u = t & 7;
        float4 v = make_float4(0.f, 0.f, 0.f, 0.f);
        if (k0 + vl < NN && n0 + 4 * u + 4 <= NN)
            v = *(const float4*)(Ab + (long)(k0 + vl) * NN + n0 + 4 * u);
        int nb = 4 * u;
        Ls[(nb + 0) * 36 + vl] = f2bf(v.x);
        Ls[(nb + 1) * 36 + vl] = f2bf(v.y);
        Ls[(nb + 2) * 36 + vl] = f2bf(v.z);
        Ls[(nb + 3) * 36 + vl] = f2bf(v.w);
    }
    __syncthreads();
    {
        int row = t >> 3, u = t & 7;
        if (n0 + row < NN)
            *(uint2*)(Ob + (long)(n0 + row) * KP + k0 + 4 * u) = *(const uint2*)(&Ls[row * 36 + 4 * u]);
    }
}

__global__ __launch_bounds__(256) void xpose_kernel(
    const float* __restrict__ x, u16* __restrict__ Xt)
{
    __shared__ u16 Ls[MM * 36];
    const int t = threadIdx.x;
    const int v0 = blockIdx.x * 32;
    const int b  = blockIdx.y;
    #pragma unroll
    for (int j = 0; j < 12; ++j) {
        int f = t + 256 * j;
        int c = f / 96;
        int r = f - c * 96;
        int vl = r / 3;
        int l3 = (r - vl * 3) * 4;
        float4 v = make_float4(0.f, 0.f, 0.f, 0.f);
        if (v0 + vl < NN)
            v = *(const float4*)(x + ((long)b * CC + c) * (NN * LLc) + (long)(v0 + vl) * LLc + l3);
        int mb = (c * LLc + l3) * 36 + vl;
        Ls[mb]       = f2bf(v.x);
        Ls[mb + 36]  = f2bf(v.y);
        Ls[mb + 72]  = f2bf(v.z);
        Ls[mb + 108] = f2bf(v.w);
    }
    __syncthreads();
    #pragma unroll
    for (int j = 0; j < 12; ++j) {
        int f = t + 256 * j;
        int row = f >> 3, u = f & 7;
        *(uint2*)(Xt + ((long)b * MM + row) * KP + v0 + 4 * u) = *(const uint2*)(&Ls[row * 36 + 4 * u]);
    }
}

__global__ __launch_bounds__(256) void wpack_kernel(
    const float* __restrict__ W, u16* __restrict__ Wp)
{
    int idx = blockIdx.x * 256 + threadIdx.x;   // < 18432
    int j    = idx & 7;
    int lane = (idx >> 3) & 63;
    int p    = (idx >> 9) & 1;
    int mt   = (idx >> 10) & 1;
    int g    = idx >> 11;
    int o  = mt * 16 + (lane & 15);
    int kk = g * 32 + (lane >> 4) * 8 + j;
    float wv = W[o * 288 + kk];
    u16 hi = f2bf(wv);
    Wp[idx] = (p == 0) ? hi : f2bf(wv - bf2f(hi));
}

// ---------------- hop GEMM v6: 128x128 tile (64-reg acc -> 4 waves/SIMD),
// 2-buffer 2-phase gload_lds schedule (proven in v4), XOR-swizzled LDS,
// bijective XCD swizzle over 3072 blocks. All operands 512-stride zero-padded.
__global__ __launch_bounds__(256, 4) void hop_fast6(
    const u16* __restrict__ Xsrc, long x_gstride, long x_bstride,
    const u16* __restrict__ At_s,   // g<3: static A, g-stride AT_ELS
    const u16* __restrict__ At_b,   // g==3: batched A, b-stride AT_ELS
    u16* __restrict__ Hout, long h_gstride)
{
    __shared__ __align__(16) u16 smem[16384];   // 2 x 16KB k-step buffers (A 8KB + X 8KB)
    u16* Ct = smem;                             // epilogue reuse [64][136]

    const int t = threadIdx.x;
    const int lane = t & 63;
    const int wv = t >> 6;
    // bijective XCD swizzle over 3072 blocks (3072 % 8 == 0); 12 tiles/(g,b) contiguous
    const int f0 = blockIdx.x + 4 * (blockIdx.y + 3 * blockIdx.z);   // 0..3071
    const int w  = (f0 & 7) * 384 + (f0 >> 3);
    const int zc = w / 12;
    const int rem = w - zc * 12;
    const int bx = rem & 3;
    const int by = rem >> 2;        // 0..2
    const int g  = zc & 3;
    const int b  = zc >> 2;
    const int n0 = bx * 128;
    const int m0 = by * 128;
    const int ln  = lane & 15;
    const int q16 = lane >> 4;

    const u16* Ab = (g < 3) ? (At_s + (long)g * AT_ELS) : (At_b + (long)b * AT_ELS);
    const u16* Xb = Xsrc + (long)g * x_gstride + (long)b * x_bstride;
    u16* Ob = Hout + (long)g * h_gstride + (long)b * ((long)MM * KP);

    // staging: per instr, wave covers 16 rows x 64B; row = (o>>6)+(lane>>2)
    const int rbase = lane >> 2;
    const int coff  = (((lane & 3) ^ ((lane >> 3) & 3)) << 3);   // inverse-swizzled src col (u16)
    const int rsel  = ((q16 ^ ((ln >> 1) & 3)) << 3);            // swizzled read col (u16)

    auto STAGE = [&](int kk, int pb) {
        #pragma unroll
        for (int j = 0; j < 4; ++j) {
            int o = (wv * 4 + j) << 10;            // byte offset in 16KB buffer
            const u16* src;
            if (o < 8192) {                         // A region: rows 0..127 (n)
                src = Ab + (long)(n0 + (o >> 6) + rbase) * KP + kk + coff;
            } else {                                // X region: rows 0..127 (m)
                src = Xb + (long)(m0 + (o >> 6) - 128 + rbase) * KP + kk + coff;
            }
            __builtin_amdgcn_global_load_lds((gu32*)src,
                (lu32*)((char*)smem + pb * 16384 + o), 16, 0, 0);
        }
    };

    f32x4 acc[2][8];
    #pragma unroll
    for (int ns = 0; ns < 2; ++ns)
        #pragma unroll
        for (int i = 0; i < 8; ++i)
            #pragma unroll
            for (int r = 0; r < 4; ++r) acc[ns][i][r] = 0.f;

    STAGE(0, 0);
    asm volatile("s_waitcnt vmcnt(0)" ::: "memory");
    __syncthreads();

    #pragma unroll 1
    for (int s = 0; s < 16; ++s) {
        const int pb = s & 1;
        if (s < 15) STAGE(32 * (s + 1), pb ^ 1);
        const u16* As = smem + pb * 8192;           // u16 units (16KB)
        const u16* Xs = As + 4096;                  // +8KB
        bf16x8 b0 = *(const bf16x8*)(&As[(wv * 32 + ln) * 32 + rsel]);
        bf16x8 b1 = *(const bf16x8*)(&As[(wv * 32 + 16 + ln) * 32 + rsel]);
        #pragma unroll
        for (int i = 0; i < 8; ++i) {
            bf16x8 af = *(const bf16x8*)(&Xs[(i * 16 + ln) * 32 + rsel]);
            acc[0][i] = __builtin_amdgcn_mfma_f32_16x16x32_bf16(af, b0, acc[0][i], 0, 0, 0);
            acc[1][i] = __builtin_amdgcn_mfma_f32_16x16x32_bf16(af, b1, acc[1][i], 0, 0, 0);
        }
        asm volatile("s_waitcnt vmcnt(0)" ::: "memory");
        __syncthreads();
    }

    // epilogue: two rounds of 64 rows; writes 512-stride rows (zeros in n>=500 pad)
    #pragma unroll
    for (int h = 0; h < 2; ++h) {
        __syncthreads();
        #pragma unroll
        for (int ns = 0; ns < 2; ++ns) {
            int col = wv * 32 + ns * 16 + ln;
            #pragma unroll
            for (int i4 = 0; i4 < 4; ++i4) {
                int rb = i4 * 16 + (lane >> 4) * 4;
                #pragma unroll
                for (int r = 0; r < 4; ++r)
                    Ct[(rb + r) * CT2_S + col] = f2bf(acc[ns][h * 4 + i4][r]);
            }
        }
        __syncthreads();
        #pragma unroll
        for (int j = 0; j < 8; ++j) {
            int f = t + 256 * j;        // 0..2047: 64 rows x 32 uint2
            int row = f >> 5, u = f & 31;
            int n = n0 + 4 * u;
            uint2 v = make_uint2(0u, 0u);
            if (n < NN) v = *(const uint2*)(&Ct[row * CT2_S + 4 * u]);
            *(uint2*)(Ob + (long)(m0 + h * 64 + row) * KP + n) = v;
        }
    }
}

// ---------------- merged hop GEMM v3 (mid-tier fallback): 192x128 tile, reg-staged
__global__ __launch_bounds__(256, 3) void hop_fast3(
    const u16* __restrict__ Xsrc, long x_gstride, long x_bstride, int x_rstride, int x_klim,
    const u16* __restrict__ At_s,
    const u16* __restrict__ At_b,
    u16* __restrict__ Hout, long h_gstride)
{
    __shared__ __align__(16) u16 smem[13056];
    u16* As = smem;          // [128][40]
    u16* Xs = smem + 5120;   // [192][40]
    u16* Ct = smem;          // [96][136]

    const int t = threadIdx.x;
    const int lane = t & 63;
    const int wv = t >> 6;
    const int f0 = blockIdx.x + 4 * blockIdx.y + 8 * blockIdx.z;
    const int w  = (f0 & 7) * 256 + (f0 >> 3);
    const int bx = w & 3;
    const int by = (w >> 2) & 1;
    const int zc = w >> 3;
    const int g  = zc & 3;
    const int b  = zc >> 2;
    const int n0 = bx * NT2;
    const int m0 = by * 192;
    const int ln = lane & 15;
    const int q8 = (lane >> 4) * 8;

    const u16* Ab = (g < 3) ? (At_s + (long)g * AT_ELS) : (At_b + (long)b * AT_ELS);
    const u16* Xb = Xsrc + (long)g * x_gstride + (long)b * x_bstride;
    u16* Ob = Hout + (long)g * h_gstride + (long)b * ((long)MM * NN);

    uint2 pa[4], px[6];
    auto loadA = [&](int k0) {
        #pragma unroll
        for (int j = 0; j < 4; ++j) {
            int f = t + 256 * j;
            int n = f >> 3, u = f & 7;
            uint2 v = make_uint2(0u, 0u);
            if (n0 + n < NN)
                v = *(const uint2*)(Ab + (long)(n0 + n) * KP + k0 + 4 * u);
            pa[j] = v;
        }
    };
    auto loadX = [&](int k0) {
        #pragma unroll
        for (int j = 0; j < 6; ++j) {
            int f = t + 256 * j;
            int r = f >> 3, u = f & 7;
            int k = k0 + 4 * u;
            uint2 v = make_uint2(0u, 0u);
            if (k < x_klim)
                v = *(const uint2*)(Xb + (long)(m0 + r) * x_rstride + k);
            px[j] = v;
        }
    };

    f32x4 acc[2][12];
    #pragma unroll
    for (int ns = 0; ns < 2; ++ns)
        #pragma unroll
        for (int i = 0; i < 12; ++i)
            #pragma unroll
            for (int r = 0; r < 4; ++r) acc[ns][i][r] = 0.f;

    loadA(0);
    loadX(0);
    #pragma unroll 1
    for (int s = 0; s < 16; ++s) {
        __syncthreads();
        #pragma unroll
        for (int j = 0; j < 4; ++j) {
            int f = t + 256 * j;
            *(uint2*)(&As[(f >> 3) * AS_S + 4 * (f & 7)]) = pa[j];
        }
        #pragma unroll
        for (int j = 0; j < 6; ++j) {
            int f = t + 256 * j;
            *(uint2*)(&Xs[(f >> 3) * XS_S + 4 * (f & 7)]) = px[j];
        }
        if (s < 15) {
            loadA(32 * (s + 1));
            loadX(32 * (s + 1));
        }
        __syncthreads();
        bf16x8 b0 = *(const bf16x8*)(&As[(wv * 32 + ln) * AS_S + q8]);
        bf16x8 b1 = *(const bf16x8*)(&As[(wv * 32 + 16 + ln) * AS_S + q8]);
        #pragma unroll
        for (int i = 0; i < 12; ++i) {
            bf16x8 af = *(const bf16x8*)(&Xs[(i * 16 + ln) * XS_S + q8]);
            acc[0][i] = __builtin_amdgcn_mfma_f32_16x16x32_bf16(af, b0, acc[0][i], 0, 0, 0);
            acc[1][i] = __builtin_amdgcn_mfma_f32_16x16x32_bf16(af, b1, acc[1][i], 0, 0, 0);
        }
    }

    #pragma unroll
    for (int h = 0; h < 2; ++h) {
        __syncthreads();
        #pragma unroll
        for (int ns = 0; ns < 2; ++ns) {
            int col = wv * 32 + ns * 16 + ln;
            #pragma unroll
            for (int i6 = 0; i6 < 6; ++i6) {
                int rb = i6 * 16 + (lane >> 4) * 4;
                #pragma unroll
                for (int r = 0; r < 4; ++r)
                    Ct[(rb + r) * CT2_S + col] = f2bf(acc[ns][h * 6 + i6][r]);
            }
        }
        __syncthreads();
        #pragma unroll
        for (int j = 0; j < 12; ++j) {
            int f = t + 256 * j;
            int row = f >> 5, u = f & 31;
            int n = n0 + 4 * u;
            if (n < NN)
                *(uint2*)(Ob + (long)(m0 + h * 96 + row) * NN + n) = *(const uint2*)(&Ct[row * CT2_S + 4 * u]);
        }
    }
}

// ---------------- MFMA mix: out[o][(l,n)] = sum_c (Whi+Wlo)[o][c] * Hcat[c][(l,n)] + bias
__global__ __launch_bounds__(512, 4) void mix_mfma(
    const u16* __restrict__ Xt,
    const u16* __restrict__ H,
    const u16* __restrict__ Wp,
    const float* __restrict__ bias,
    float* __restrict__ out,
    long h_gs, long h_bs, int h_rs)
{
    __shared__ __align__(16) char smem[50176];   // tile: 384*64*2 = 49152 B ; Ct reuse
    u16*   Ls = (u16*)smem;
    float* Ct = (float*)smem;

    const int t   = threadIdx.x;
    const int wg  = blockIdx.y * 8 + blockIdx.x;
    const int swz = (wg & 7) * 64 + (wg >> 3);   // chunked XCD swizzle
    const int bx  = swz & 7;
    const int b   = swz >> 3;
    const int n0  = bx * 64;
    const int w    = t >> 6;          // wave 0..7
    const int lane = t & 63;
    const int kq   = lane >> 4;
    const int ln   = lane & 15;
    const int srow   = lane >> 3;
    const int schunk = (lane & 7) * 8;

    f32x4 acc[6][2];
    #pragma unroll
    for (int i = 0; i < 6; ++i)
        #pragma unroll
        for (int m = 0; m < 2; ++m)
            #pragma unroll
            for (int r = 0; r < 4; ++r) acc[i][m][r] = 0.f;

    #pragma unroll 1
    for (int g = 0; g < 9; ++g) {
        const u16* base; int rs;
        if (g == 0) { base = Xt + (long)b * (MM * KP); rs = KP; }
        else {
            int gg = g - 1;
            int buf = (gg & 1) ? 4 + (gg >> 1) : (gg >> 1);
            base = H + (long)buf * h_gs + (long)b * h_bs; rs = h_rs;
        }
        __syncthreads();
        #pragma unroll
        for (int i = 0; i < 6; ++i) {
            int r0 = (w * 6 + i) * 8;
            const u16* src = base + (long)(r0 + srow) * rs + n0 + schunk;
            __builtin_amdgcn_global_load_lds((gu32*)src, (lu32*)(Ls + r0 * 64), 16, 0, 0);
        }
        asm volatile("s_waitcnt vmcnt(0)" ::: "memory");
        __syncthreads();
        uint4 wf[2][2];
        #pragma unroll
        for (int mt = 0; mt < 2; ++mt)
            #pragma unroll
            for (int p = 0; p < 2; ++p)
                wf[mt][p] = *(const uint4*)(Wp + ((((g * 2 + mt) * 2 + p) * 64 + lane) * 8));
        #pragma unroll
        for (int i = 0; i < 6; ++i) {
            int ct = w * 6 + i;
            int off0 = kq * 6144 + (ct >> 2) * 64 + (ct & 3) * 16 + ln;
            union { u16 s[8]; bf16x8 v; } fb;
            #pragma unroll
            for (int j = 0; j < 8; ++j) fb.s[j] = Ls[off0 + j * 768];
            #pragma unroll
            for (int mt = 0; mt < 2; ++mt) {
                acc[i][mt] = __builtin_amdgcn_mfma_f32_16x16x32_bf16(*(const bf16x8*)&wf[mt][0], fb.v, acc[i][mt], 0, 0, 0);
                acc[i][mt] = __builtin_amdgcn_mfma_f32_16x16x32_bf16(*(const bf16x8*)&wf[mt][1], fb.v, acc[i][mt], 0, 0, 0);
            }
        }
    }

    #pragma unroll
    for (int mt = 0; mt < 2; ++mt) {
        __syncthreads();
        #pragma unroll
        for (int i = 0; i < 6; ++i) {
            int col = (w * 6 + i) * 16 + ln;
            #pragma unroll
            for (int r = 0; r < 4; ++r)
                Ct[(kq * 4 + r) * 781 + col] = acc[i][mt][r];
        }
        __syncthreads();
        int o16 = t >> 5, u = t & 31;
        int og = mt * 16 + o16;
        float bs = bias[og];
        float* ob = out + (((long)b * CC + og) * NN + n0) * 12L;
        #pragma unroll
        for (int j2 = 0; j2 < 2; ++j2) {
            int n = u + 32 * j2;
            if (n0 + n < NN) {
                float v[12];
                #pragma unroll
                for (int l = 0; l < 12; ++l) v[l] = Ct[o16 * 781 + l * 64 + n] + bs;
                #pragma unroll
                for (int q = 0; q < 3; ++q)
                    *(float4*)(ob + (long)n * 12 + q * 4) = *(const float4*)&v[q * 4];
            }
        }
    }
}

// ---------------- single-pass mix (mid-tier ws, VALU)
__global__ __launch_bounds__(256, 3) void mix_all(
    const u16* __restrict__ Xt,
    const u16* __restrict__ H,
    const float* __restrict__ W,
    const float* __restrict__ bias,
    float* __restrict__ out)
{
    __shared__ __align__(16) float smem[96 * 36 + 288 * 33];
    float* ts = smem;
    float* Ws = smem + 96 * 36;

    const int t  = threadIdx.x;
    const int b  = blockIdx.y;
    const int w0 = blockIdx.x * 32;
    const int o  = t & 31;
    const int wq = t >> 5;
    const int w4 = wq * 4;
    const long HBUF = (long)64 * MM * NN;

    #pragma unroll
    for (int j = 0; j < 36; ++j) {
        int f = t + 256 * j;
        int oo = f & 31, ci = f >> 5;
        Ws[ci * 33 + oo] = W[oo * 288 + ci];
    }

    float acc[4][12];
    #pragma unroll
    for (int k = 0; k < 4; ++k)
        #pragma unroll
        for (int l = 0; l < 12; ++l) acc[k][l] = 0.f;

    uint2 px[3];
    auto loadq = [&](int q) {
        int g = q >> 2, c0 = (q & 3) << 3;
        const u16* base; int rs;
        if (g == 0) { base = Xt + (long)b * (MM * KP); rs = KP; }
        else {
            int gg = g - 1, i = gg >> 1;
            int buf = (gg & 1) ? 4 + i : i;
            base = H + (long)buf * HBUF + (long)b * ((long)MM * NN); rs = NN;
        }
        int m0c = c0 * 12;
        #pragma unroll
        for (int j = 0; j < 3; ++j) {
            int f = t + 256 * j;
            int r = f >> 3, u = f & 7;
            px[j] = *(const uint2*)(base + (long)(m0c + r) * rs + w0 + 4 * u);
        }
    };

    loadq(0);
    #pragma unroll 1
    for (int q = 0; q < 36; ++q) {
        __syncthreads();
        #pragma unroll
        for (int j = 0; j < 3; ++j) {
            int f = t + 256 * j;
            int r = f >> 3, u = f & 7;
            uint2 raw = px[j];
            float4 v = make_float4(bf2f((u16)(raw.x & 0xffffu)), bf2f((u16)(raw.x >> 16)),
                                   bf2f((u16)(raw.y & 0xffffu)), bf2f((u16)(raw.y >> 16)));
            *(float4*)(&ts[r * 36 + 4 * u]) = v;
        }
        if (q < 35) loadq(q + 1);
        __syncthreads();
        int g = q >> 2, c0 = (q & 3) << 3;
        #pragma unroll 1
        for (int cl = 0; cl < 8; ++cl) {
            float wgt = Ws[(g * 32 + c0 + cl) * 33 + o];
            #pragma unroll
            for (int l = 0; l < 12; ++l) {
                float4 h = *(const float4*)(&ts[(cl * 12 + l) * 36 + w4]);
                acc[0][l] += wgt * h.x;
                acc[1][l] += wgt * h.y;
                acc[2][l] += wgt * h.z;
                acc[3][l] += wgt * h.w;
            }
        }
    }

    #pragma unroll 1
    for (int r = 0; r < 4; ++r) {
        __syncthreads();
        if ((o >> 3) == r) {
            int ol = o & 7;
            #pragma unroll
            for (int k = 0; k < 4; ++k)
                #pragma unroll
                for (int l = 0; l < 12; ++l)
                    ts[ol * 388 + (w4 + k) * 12 + l] = acc[k][l];
        }
        __syncthreads();
        #pragma unroll
        for (int j = 0; j < 3; ++j) {
            int f4 = t + 256 * j;
            int ol = f4 / 96;
            int rem = f4 - ol * 96;
            int w  = rem / 3;
            int lq = rem - w * 3;
            if (w0 + w < NN) {
                float4 v = *(const float4*)(&ts[ol * 388 + w * 12 + lq * 4]);
                float bs = bias[r * 8 + ol];
                v.x += bs; v.y += bs; v.z += bs; v.w += bs;
                *(float4*)(out + (((long)b * CC + r * 8 + ol) * NN + w0 + w) * LLc + lq * 4) = v;
            }
        }
    }
}

// ======================================================================
// Fallback path (R3-equivalent) — used when ws < 256 MB tier
// ======================================================================
__global__ __launch_bounds__(256, 4) void hop_fast(
    const u16* __restrict__ Xsrc, long x_bstride, int x_rstride, int x_klim,
    const u16* __restrict__ At,   long a_bstride,
    u16* __restrict__ hout)
{
    __shared__ __align__(16) u16 smem[13056];
    u16* As = smem;
    u16* Xs = smem + 5120;
    u16* Ct = smem;

    const int t = threadIdx.x;
    const int lane = t & 63;
    const int wv = t >> 6;
    const int n0 = blockIdx.x * NT2;
    const int m0 = blockIdx.y * MT;
    const int b  = blockIdx.z;
    const int ln = lane & 15;
    const int q8 = (lane >> 4) * 8;

    const u16* Ab = At + (long)b * a_bstride;
    const u16* Xb = Xsrc + (long)b * x_bstride;

    uint2 pa[4], px[3];
    auto loadA = [&](int k0) {
        #pragma unroll
        for (int j = 0; j < 4; ++j) {
            int f = t + 256 * j;
            int n = f >> 3, u = f & 7;
            uint2 v = make_uint2(0u, 0u);
            if (n0 + n < NN)
                v = *(const uint2*)(Ab + (long)(n0 + n) * KP + k0 + 4 * u);
            pa[j] = v;
        }
    };
    auto loadX = [&](int k0) {
        #pragma unroll
        for (int j = 0; j < 3; ++j) {
            int f = t + 256 * j;
            int r = f >> 3, u = f & 7;
            int k = k0 + 4 * u;
            uint2 v = make_uint2(0u, 0u);
            if (k < x_klim)
                v = *(const uint2*)(Xb + (long)(m0 + r) * x_rstride + k);
            px[j] = v;
        }
    };

    f32x4 acc[2][6];
    #pragma unroll
    for (int ns = 0; ns < 2; ++ns)
        #pragma unroll
        for (int i = 0; i < 6; ++i)
            #pragma unroll
            for (int r = 0; r < 4; ++r) acc[ns][i][r] = 0.f;

    loadA(0);
    loadX(0);
    #pragma unroll 1
    for (int s = 0; s < 16; ++s) {
        __syncthreads();
        #pragma unroll
        for (int j = 0; j < 4; ++j) {
            int f = t + 256 * j;
            *(uint2*)(&As[(f >> 3) * AS_S + 4 * (f & 7)]) = pa[j];
        }
        #pragma unroll
        for (int j = 0; j < 3; ++j) {
            int f = t + 256 * j;
            *(uint2*)(&Xs[(f >> 3) * XS_S + 4 * (f & 7)]) = px[j];
        }
        if (s < 15) {
            loadA(32 * (s + 1));
            loadX(32 * (s + 1));
        }
        __syncthreads();
        bf16x8 af[6];
        #pragma unroll
        for (int i = 0; i < 6; ++i)
            af[i] = *(const bf16x8*)(&Xs[(i * 16 + ln) * XS_S + q8]);
        #pragma unroll
        for (int ns = 0; ns < 2; ++ns) {
            bf16x8 bfr = *(const bf16x8*)(&As[(wv * 32 + ns * 16 + ln) * AS_S + q8]);
            #pragma unroll
            for (int i = 0; i < 6; ++i)
                acc[ns][i] = __builtin_amdgcn_mfma_f32_16x16x32_bf16(af[i], bfr, acc[ns][i], 0, 0, 0);
        }
    }

    __syncthreads();
    #pragma unroll
    for (int ns = 0; ns < 2; ++ns) {
        int col = wv * 32 + ns * 16 + ln;
        #pragma unroll
        for (int i = 0; i < 6; ++i) {
            int rb = i * 16 + (lane >> 4) * 4;
            #pragma unroll
            for (int r = 0; r < 4; ++r)
                Ct[(rb + r) * CT2_S + col] = f2bf(acc[ns][i][r]);
        }
    }
    __syncthreads();
    u16* Ob = hout + (long)b * ((long)MM * NN);
    #pragma unroll
    for (int j = 0; j < 12; ++j) {
        int f = t + 256 * j;
        int row = f >> 5, u = f & 31;
        int n = n0 + 4 * u;
        if (n < NN)
            *(uint2*)(Ob + (long)(m0 + row) * NN + n) = *(const uint2*)(&Ct[row * CT2_S + 4 * u]);
    }
}

__global__ __launch_bounds__(256, 2) void mix_kernel(
    const float* __restrict__ x,
    const u16* __restrict__ h1,
    const u16* __restrict__ h2,
    const float* __restrict__ W,
    const float* __restrict__ bias,
    int blk1, int blk2,
    float* __restrict__ out, int init)
{
    __shared__ __align__(16) float smem[CC * TS_S + 3 * 1056];
    float* ts = smem;
    float* Ws = smem + CC * TS_S;

    const int t = threadIdx.x;
    const int b = blockIdx.y;
    const int w0 = blockIdx.x * 32;
    const int o  = t & 15;
    const int wg = (t >> 4) & 7;
    const int lh = t >> 7;

    #pragma unroll
    for (int j = 0; j < 4; ++j) {
        int f = t + 256 * j;
        int oo = f & 31, c = f >> 5;
        Ws[c * 33 + oo]        = W[oo * 288 + blk1 * 32 + c];
        Ws[1056 + c * 33 + oo] = W[oo * 288 + blk2 * 32 + c];
        if (init) Ws[2112 + c * 33 + oo] = W[oo * 288 + c];
    }

    float acc2[2][4][6];
    #pragma unroll
    for (int a = 0; a < 2; ++a)
        #pragma unroll
        for (int q = 0; q < 4; ++q)
            #pragma unroll
            for (int l = 0; l < 6; ++l) acc2[a][q][l] = 0.f;

    auto stage_h = [&](const u16* h) {
        #pragma unroll
        for (int j = 0; j < 12; ++j) {
            int f = t + 256 * j;
            int row = f >> 3, u = f & 7;
            int w = w0 + 4 * u;
            uint2 raw = make_uint2(0u, 0u);
            if (w < NN)
                raw = *(const uint2*)(h + ((long)b * MM + row) * NN + w);
            int c = row / 12;
            int l = row - c * 12;
            float* dst = &ts[c * TS_S + l * 32 + 4 * u];
            dst[0] = bf2f((u16)(raw.x & 0xffffu));
            dst[1] = bf2f((u16)(raw.x >> 16));
            dst[2] = bf2f((u16)(raw.y & 0xffffu));
            dst[3] = bf2f((u16)(raw.y >> 16));
        }
    };
    auto accum = [&](const float* Wg) {
        for (int c = 0; c < CC; ++c) {
            float w1 = Wg[c * 33 + o];
            float w2 = Wg[c * 33 + o + 16];
            #pragma unroll
            for (int l6 = 0; l6 < 6; ++l6) {
                const float4 hv = *(const float4*)(&ts[c * TS_S + (lh * 6 + l6) * 32 + wg * 4]);
                acc2[0][0][l6] += w1 * hv.x;
                acc2[0][1][l6] += w1 * hv.y;
                acc2[0][2][l6] += w1 * hv.z;
                acc2[0][3][l6] += w1 * hv.w;
                acc2[1][0][l6] += w2 * hv.x;
                acc2[1][1][l6] += w2 * hv.y;
                acc2[1][2][l6] += w2 * hv.z;
                acc2[1][3][l6] += w2 * hv.w;
            }
        }
    };

    if (init) {
        #pragma unroll
        for (int j = 0; j < 12; ++j) {
            int f = t + 256 * j;
            int c = f / 96;
            int r = f - c * 96;
            int w = r / 3;
            int q = r - w * 3;
            float4 v = make_float4(0.f, 0.f, 0.f, 0.f);
            if (w0 + w < NN)
                v = *(const float4*)(x + ((long)b * CC + c) * (NN * LLc) + (long)(w0 + w) * LLc + q * 4);
            float* dst = &ts[c * TS_S + (q * 4) * 32 + w];
            dst[0]  = v.x; dst[32] = v.y; dst[64] = v.z; dst[96] = v.w;
        }
        __syncthreads();
        accum(Ws + 2112);
        __syncthreads();
    }
    stage_h(h1);
    __syncthreads();
    accum(Ws);
    __syncthreads();
    stage_h(h2);
    __syncthreads();
    accum(Ws + 1056);

    #pragma unroll
    for (int oh = 0; oh < 2; ++oh) {
        int oo = o + 16 * oh;
        float bs = init ? bias[oo] : 0.f;
        #pragma unroll
        for (int q = 0; q < 4; ++q) {
            int w = w0 + wg * 4 + q;
            if (w < NN) {
                float* op = out + ((long)b * CC + oo) * (NN * LLc) + (long)w * LLc + lh * 6;
                #pragma unroll
                for (int p = 0; p < 3; ++p) {
                    float2* pp = (float2*)op + p;
                    float2 v;
                    if (init) {
                        v.x = bs + acc2[oh][q][2 * p];
                        v.y = bs + acc2[oh][q][2 * p + 1];
                    } else {
                        v = *pp;
                        v.x += acc2[oh][q][2 * p];
                        v.y += acc2[oh][q][2 * p + 1];
                    }
                    *pp = v;
                }
            }
        }
    }
}

extern "C" void kernel_launch(void* const* d_in, const int* in_sizes, int n_in,
                              void* d_out, int out_size, void* d_ws, size_t ws_size,
                              hipStream_t stream) {
    const float* x    = (const float*)d_in[0];
    const float* A0   = (const float*)d_in[1];
    const float* A1   = (const float*)d_in[2];
    const float* A2   = (const float*)d_in[3];
    const float* A3   = (const float*)d_in[4];
    const float* W    = (const float*)d_in[5];
    const float* bias = (const float*)d_in[6];
    float* out = (float*)d_out;
    char* ws = (char*)d_ws;

    const size_t HBUF_ELS  = (size_t)64 * MM * NN;          // 12,288,000
    const size_t H8_BYTES  = 8 * HBUF_ELS * 2;              // 196,608,000
    const size_t AT_BYTES  = (size_t)AT_ELS * 2;            // 512,000
    const size_t A3T_BYTES = 64 * AT_BYTES;                 // 32,768,000
    const size_t XT_BYTES  = (size_t)64 * MM * KP * 2;      // 25,165,824
    const size_t need2 = H8_BYTES + 3 * AT_BYTES + A3T_BYTES + XT_BYTES;  // 256,077,824
    const size_t WPK_BYTES = 36864;
    const size_t need3 = need2 + WPK_BYTES;
    // padded-H tier: all M x N buffers [384][512]
    const size_t HB2_ELS  = (size_t)64 * MM * KP;           // 12,582,912 per buffer
    const size_t H8B_PAD  = 8 * HB2_ELS * 2;                // 201,326,592
    const size_t need4 = H8B_PAD + 3 * AT_BYTES + A3T_BYTES + XT_BYTES + WPK_BYTES; // 260,833,280

    dim3 blk(256);

    if (ws_size >= need4) {
        // ---------- fastest path: merged prep + 128x128 4-wave/SIMD hops + MFMA mix ----------
        u16* Hb   = (u16*)ws;
        u16* At_s = (u16*)(ws + H8B_PAD);
        u16* A3t  = At_s + 3L * AT_ELS;
        u16* Xt   = (u16*)(ws + H8B_PAD + 3 * AT_BYTES + A3T_BYTES);
        u16* Wpk  = Xt + (size_t)64 * MM * KP;

        prep_all<<<dim3(18248), blk, 0, stream>>>(x, A0, A1, A2, A3, At_s, A3t, Xt, W, Wpk);
        hop_fast6<<<dim3(4, 3, 256), blk, 0, stream>>>(
            Xt, 0L, (long)MM * KP, At_s, A3t, Hb, (long)HB2_ELS);
        hop_fast6<<<dim3(4, 3, 256), blk, 0, stream>>>(
            Hb, (long)HB2_ELS, (long)MM * KP, At_s, A3t,
            Hb + 4 * HB2_ELS, (long)HB2_ELS);
        mix_mfma<<<dim3(8, 64), dim3(512), 0, stream>>>(
            Xt, Hb, Wpk, bias, out, (long)HB2_ELS, (long)MM * KP, KP);
        return;
    }

    dim3 hgrid(4, 2, 256);

    if (ws_size >= need3) {
        // ---------- round-3 proven path: reg-staged hops (500-stride H) + MFMA mix ----------
        u16* Hb   = (u16*)ws;
        u16* At_s = (u16*)(ws + H8_BYTES);
        u16* A3t  = At_s + 3L * AT_ELS;
        u16* Xt   = (u16*)(ws + H8_BYTES + 3 * AT_BYTES + A3T_BYTES);
        u16* Wpk  = (u16*)(ws + need2);

        atrans_all<<<dim3(16, 16, 67), blk, 0, stream>>>(A0, A1, A2, A3, At_s, A3t);
        xpose_kernel<<<dim3(16, 64), blk, 0, stream>>>(x, Xt);
        wpack_kernel<<<dim3(72), blk, 0, stream>>>(W, Wpk);
        hop_fast3<<<hgrid, blk, 0, stream>>>(
            Xt, 0L, (long)MM * KP, KP, KP, At_s, A3t, Hb, (long)HBUF_ELS);
        hop_fast3<<<hgrid, blk, 0, stream>>>(
            Hb, (long)HBUF_ELS, (long)MM * NN, NN, NN, At_s, A3t,
            Hb + 4 * HBUF_ELS, (long)HBUF_ELS);
        mix_mfma<<<dim3(8, 64), dim3(512), 0, stream>>>(
            Xt, Hb, Wpk, bias, out, (long)HBUF_ELS, (long)MM * NN, NN);
        return;
    }

    if (ws_size >= need2) {
        // ---------- mid tier: VALU mix ----------
        u16* H    = (u16*)ws;
        u16* At_s = (u16*)(ws + H8_BYTES);
        u16* A3t  = At_s + 3L * AT_ELS;
        u16* Xt   = (u16*)(ws + H8_BYTES + 3 * AT_BYTES + A3T_BYTES);

        atrans_all<<<dim3(16, 16, 67), blk, 0, stream>>>(A0, A1, A2, A3, At_s, A3t);
        xpose_kernel<<<dim3(16, 64), blk, 0, stream>>>(x, Xt);
        hop_fast3<<<hgrid, blk, 0, stream>>>(
            Xt, 0L, (long)MM * KP, KP, KP, At_s, A3t, H, (long)HBUF_ELS);
        hop_fast3<<<hgrid, blk, 0, stream>>>(
            H, (long)HBUF_ELS, (long)MM * NN, NN, NN, At_s, A3t,
            H + 4 * HBUF_ELS, (long)HBUF_ELS);
        mix_all<<<dim3(16, 64), blk, 0, stream>>>(Xt, H, W, bias, out);
        return;
    }

    // ---------- fallback (R3 path) ----------
    const size_t H_BYTES   = HBUF_ELS * 2;
    const size_t need_at   = 2 * H_BYTES + 3 * AT_BYTES + A3T_BYTES;

    u16* H1 = (u16*)ws;
    u16* H2 = (u16*)(ws + H_BYTES);
    u16* At0 = (u16*)(ws + 2 * H_BYTES);
    u16* A3t = At0 + 3L * AT_ELS;
    u16* Xt  = (u16*)(ws + need_at);

    dim3 fgrid(4, 4, 64);
    dim3 mgrid(16, 64);

    xpose_kernel<<<dim3(16, 64), blk, 0, stream>>>(x, Xt);
    atrans_all<<<dim3(16, 16, 67), blk, 0, stream>>>(A0, A1, A2, A3, At0, A3t);

    const long XT_BS = (long)MM * KP;
    const long H_BS  = (long)MM * NN;
    u16* Atp[4] = {At0, At0 + (long)AT_ELS, At0 + 2L * AT_ELS, A3t};

    for (int i = 0; i < 4; ++i) {
        long a_bs = (i == 3) ? (long)AT_ELS : 0;
        hop_fast<<<fgrid, blk, 0, stream>>>(Xt, XT_BS, KP, KP, Atp[i], a_bs, H1);
        hop_fast<<<fgrid, blk, 0, stream>>>(H1, H_BS, NN, NN, Atp[i], a_bs, H2);
        mix_kernel<<<mgrid, blk, 0, stream>>>(i == 0 ? x : nullptr, H1, H2, W, bias,
                                              2 * i + 1, 2 * i + 2, out, i == 0 ? 1 : 0);
    }
}